// Round 5
// baseline (139.541 us; speedup 1.0000x reference)
//
#include <hip/hip_runtime.h>
#include <stdint.h>

#define B_SZ 2
#define T_SZ 2048
#define DMODEL 1024
#define HCNT 16
#define HD 64
#define MROWS (B_SZ * T_SZ)  // 4096

typedef __attribute__((ext_vector_type(8))) __bf16 bf16x8;
typedef __attribute__((ext_vector_type(4))) __bf16 bf16x4;
typedef __attribute__((ext_vector_type(4))) float f32x4;
typedef __attribute__((ext_vector_type(8))) unsigned short u16x8;

__device__ __forceinline__ unsigned short f2bf(float f) {
  union { float f; uint32_t u; } v; v.f = f;
  uint32_t u = v.u;
  u += 0x7fffu + ((u >> 16) & 1u);
  return (unsigned short)(u >> 16);
}

__device__ __forceinline__ float fexp2(float x) {
#if __has_builtin(__builtin_amdgcn_exp2f)
  return __builtin_amdgcn_exp2f(x);
#else
  return exp2f(x);
#endif
}

__device__ __forceinline__ void gld_lds16(const void* g, void* l) {
  __builtin_amdgcn_global_load_lds((__attribute__((address_space(1))) void*)(uintptr_t)g,
                                   (__attribute__((address_space(3))) void*)l, 16, 0, 0);
}

// ---------------- fp32 -> bf16 convert (both weight tensors, one launch) ----
__global__ __launch_bounds__(256)
void cvt_all(const float* __restrict__ qkv_w, const float* __restrict__ out_w,
             unsigned short* __restrict__ dst) {
  int i = blockIdx.x * 256 + threadIdx.x;
  const int n1 = 3 * DMODEL * DMODEL / 4;
  float4 v = (i < n1) ? ((const float4*)qkv_w)[i] : ((const float4*)out_w)[i - n1];
  ushort4 o;
  o.x = f2bf(v.x); o.y = f2bf(v.y); o.z = f2bf(v.z); o.w = f2bf(v.w);
  ((ushort4*)dst)[i] = o;
}

// ---------------- RMSNorm (fp32 in, bf16 out) ----------------
__global__ __launch_bounds__(256)
void rmsnorm_bf16(const float* __restrict__ x, const float* __restrict__ w,
                  unsigned short* __restrict__ xn) {
  const int row = blockIdx.x;
  const int t = threadIdx.x;
  float4 v = ((const float4*)(x + (size_t)row * DMODEL))[t];
  float ss = v.x * v.x + v.y * v.y + v.z * v.z + v.w * v.w;
#pragma unroll
  for (int o = 1; o < 64; o <<= 1) ss += __shfl_xor(ss, o, 64);
  __shared__ float red[4];
  if ((t & 63) == 0) red[t >> 6] = ss;
  __syncthreads();
  float tot = red[0] + red[1] + red[2] + red[3];
  float scale = rsqrtf(tot * (1.0f / (float)DMODEL) + 1e-6f);
  float4 wv = ((const float4*)w)[t];
  ushort4 o;
  o.x = f2bf(v.x * scale * wv.x);
  o.y = f2bf(v.y * scale * wv.y);
  o.z = f2bf(v.z * scale * wv.z);
  o.w = f2bf(v.w * scale * wv.w);
  ((ushort4*)(xn + (size_t)row * DMODEL))[t] = o;
}

// ---------------- bf16 NT GEMM: C[M][N] = A[M][K] * B[N][K]^T, BK=64 --------
__device__ __forceinline__ void stage128x64(const unsigned short* g, int ldg,
                                            unsigned short* lds, int tid) {
  const int wave = tid >> 6;
#pragma unroll
  for (int i = 0; i < 4; ++i) {
    const unsigned short* gp = g + (size_t)(i * 32 + (tid >> 3)) * ldg + (tid & 7) * 8;
    gld_lds16(gp, lds + i * 2048 + wave * 512);
  }
}

template <int F32OUT>
__global__ __launch_bounds__(256, 2)
void gemm_bt(const unsigned short* __restrict__ A, const unsigned short* __restrict__ B,
             void* __restrict__ Cv, int M, int N, int K, int nbx) {
  __shared__ __align__(16) unsigned short As[2][128 * 64];
  __shared__ __align__(16) unsigned short Bs[2][128 * 64];
  const int t = threadIdx.x, wave = t >> 6, lane = t & 63;
  const int cpx = gridDim.x >> 3;
  const int swz = (blockIdx.x & 7) * cpx + (blockIdx.x >> 3);
  const int m0 = (swz / nbx) * 128, n0 = (swz % nbx) * 128;
  const int wr = wave >> 1, wc = wave & 1;
  const int c = lane & 15, qg = lane >> 4;
  f32x4 acc[4][4] = {};
  const int nk = K >> 6;
  stage128x64(A + (size_t)m0 * K, K, As[0], t);
  stage128x64(B + (size_t)n0 * K, K, Bs[0], t);
  __syncthreads();
  int buf = 0;
  for (int kt = 0; kt < nk; ++kt) {
    if (kt + 1 < nk) {
      stage128x64(A + (size_t)m0 * K + (kt + 1) * 64, K, As[buf ^ 1], t);
      stage128x64(B + (size_t)n0 * K + (kt + 1) * 64, K, Bs[buf ^ 1], t);
    }
#pragma unroll
    for (int kk = 0; kk < 2; ++kk) {
      bf16x8 af[4], bfr[4];
#pragma unroll
      for (int mi = 0; mi < 4; ++mi)
        af[mi] = *(const bf16x8*)&As[buf][(wr * 64 + mi * 16 + c) * 64 + kk * 32 + qg * 8];
#pragma unroll
      for (int ni = 0; ni < 4; ++ni)
        bfr[ni] = *(const bf16x8*)&Bs[buf][(wc * 64 + ni * 16 + c) * 64 + kk * 32 + qg * 8];
#pragma unroll
      for (int mi = 0; mi < 4; ++mi)
#pragma unroll
        for (int ni = 0; ni < 4; ++ni)
          acc[mi][ni] = __builtin_amdgcn_mfma_f32_16x16x32_bf16(af[mi], bfr[ni], acc[mi][ni], 0, 0, 0);
    }
    __syncthreads();
    buf ^= 1;
  }
  const int cr = qg * 4;
#pragma unroll
  for (int mi = 0; mi < 4; ++mi)
#pragma unroll
    for (int ni = 0; ni < 4; ++ni) {
      int row = m0 + wr * 64 + mi * 16 + cr;
      int col = n0 + wc * 64 + ni * 16 + c;
      if (F32OUT) {
        float* C = (float*)Cv;
#pragma unroll
        for (int r = 0; r < 4; ++r) C[(size_t)(row + r) * N + col] = acc[mi][ni][r];
      } else {
        unsigned short* C = (unsigned short*)Cv;
#pragma unroll
        for (int r = 0; r < 4; ++r) C[(size_t)(row + r) * N + col] = f2bf(acc[mi][ni][r]);
      }
    }
}

// ---------------- causal flash attention v5: fused q-tile pair ----------------
// 256 blocks (1/CU) x 512 threads (8 waves). Block (bh, p) owns q-tiles p and
// 15-p sharing ONE K/V stream (16-p k-tiles). Each wave: 16 rows of small tile
// (mi=0, active for t<=p) + 16 rows of big tile (mi=1, always). Total mi-units
// = 17 for every p -> perfectly uniform blocks, zero idle waves. One barrier
// per k-tile; K via global_load_lds (dbuf), V reg-staged (T14, dbuf).
__global__ __launch_bounds__(512, 2)
void attn_causal(const unsigned short* __restrict__ qkv, unsigned short* __restrict__ ctx) {
  __shared__ __align__(16) unsigned short Ks[2][128 * 64];     // 32 KB
  __shared__ __align__(16) unsigned short Vt[2][2][64 * 72];   // 36.9 KB
  __shared__ __align__(16) unsigned short Pl[8][32 * 136];     // 69.6 KB
  const int tid = threadIdx.x, wave = tid >> 6, lane = tid & 63;
  const int id = blockIdx.x;
  const int bh = (id & 7) | ((id >> 6) << 3);   // same bh -> same XCD
  const int p = (id >> 3) & 7;
  const int b = bh >> 4, h = bh & 15;
  const int q0a = p * 128 + wave * 16;          // mi=0 (small tile) rows
  const int q0b = (15 - p) * 128 + wave * 16;   // mi=1 (big tile) rows
  const int nit = 16 - p;
  const int c = lane & 15, qg = lane >> 4;
  const size_t base = (size_t)b * T_SZ * 3 * DMODEL;
  const int koffK = DMODEL + h * HD;
  const int koffV = 2 * DMODEL + h * HD;

  // Q fragments, pre-scaled by 0.125 * log2(e)
  const float QSC = 0.125f * 1.4426950408889634f;
  bf16x8 aq[2][2];
#pragma unroll
  for (int mi = 0; mi < 2; ++mi)
#pragma unroll
    for (int kk = 0; kk < 2; ++kk) {
      int q = (mi ? q0b : q0a) + c;
      bf16x8 f = *(const bf16x8*)(qkv + base + (size_t)q * 3 * DMODEL + h * HD + kk * 32 + qg * 8);
#pragma unroll
      for (int j = 0; j < 8; ++j) f[j] = (__bf16)((float)f[j] * QSC);
      aq[mi][kk] = f;
    }

  float mst[2] = {-3e38f, -3e38f}, lst[2] = {0.f, 0.f};
  f32x4 aco[2][4];
#pragma unroll
  for (int mi = 0; mi < 2; ++mi)
#pragma unroll
    for (int nd = 0; nd < 4; ++nd)
#pragma unroll
      for (int r = 0; r < 4; ++r) aco[mi][nd][r] = 0.f;

  auto stageK = [&](int kb, int bufi) {
#pragma unroll
    for (int i = 0; i < 2; ++i) {
      int row = i * 64 + (tid >> 3);
      gld_lds16(qkv + base + (size_t)(kb + row) * 3 * DMODEL + koffK + (((tid & 7) ^ (row & 7)) << 3),
                &Ks[bufi][i * 4096 + (wave << 9)]);
    }
  };
  auto loadV = [&](int kb, u16x8* v) {
#pragma unroll
    for (int i = 0; i < 2; ++i)
      v[i] = *(const u16x8*)(qkv + base + (size_t)(kb + i * 64 + (tid >> 3)) * 3 * DMODEL + koffV + (tid & 7) * 8);
  };
  auto writeV = [&](int bufi, const u16x8* v) {
#pragma unroll
    for (int i = 0; i < 2; ++i) {
      int kv = tid >> 3;              // k within chunk i (chunk = i*64)
#pragma unroll
      for (int j = 0; j < 8; ++j) {
        int dd = (tid & 7) * 8 + j;
        int f = (tid & 7) ^ j;        // ((dd>>3)^dd)&7
        Vt[bufi][i][dd * 72 + ((((kv >> 3) ^ f) << 3) | (kv & 7))] = v[i][j];
      }
    }
  };

  auto softmaxRow = [&](int mi, f32x4 s[8][2]) {
    float rm = -3e38f;
#pragma unroll
    for (int ni = 0; ni < 8; ++ni)
#pragma unroll
      for (int r = 0; r < 4; ++r) rm = fmaxf(rm, s[ni][mi][r]);
    rm = fmaxf(rm, __shfl_xor(rm, 16, 64));
    rm = fmaxf(rm, __shfl_xor(rm, 32, 64));
    float mo = mst[mi];
    float mn = mo;
    if (__any(rm > mo + 11.5f)) {
      mn = fmaxf(mo, rm);
      float corr = fexp2(mo - mn);
      lst[mi] *= corr;
      mst[mi] = mn;
#pragma unroll
      for (int r = 0; r < 4; ++r) {
        float cr = __shfl(corr, qg * 20 + r, 64);
#pragma unroll
        for (int nd = 0; nd < 4; ++nd) aco[mi][nd][r] *= cr;
      }
    }
    float rs = 0.f;
#pragma unroll
    for (int ni = 0; ni < 8; ++ni)
#pragma unroll
      for (int r = 0; r < 4; ++r) {
        float pv = fexp2(s[ni][mi][r] - mn);
        s[ni][mi][r] = pv;
        rs += pv;
      }
    rs += __shfl_xor(rs, 16, 64);
    rs += __shfl_xor(rs, 32, 64);
    lst[mi] += rs;
  };

  auto computeTile = [&](int kb, int kbuf, bool both, bool maskA, bool maskB) {
    f32x4 s[8][2] = {};
    __builtin_amdgcn_s_setprio(1);
#pragma unroll
    for (int kk = 0; kk < 2; ++kk) {
      bf16x8 bk[8];
#pragma unroll
      for (int ni = 0; ni < 8; ++ni) {
        int row = ni * 16 + c;
        int crd = kk * 4 + qg;
        bk[ni] = *(const bf16x8*)&Ks[kbuf][row * 64 + ((crd ^ (row & 7)) << 3)];
      }
#pragma unroll
      for (int ni = 0; ni < 8; ++ni)
        s[ni][1] = __builtin_amdgcn_mfma_f32_16x16x32_bf16(bk[ni], aq[1][kk], s[ni][1], 0, 0, 0);
      if (both)
#pragma unroll
        for (int ni = 0; ni < 8; ++ni)
          s[ni][0] = __builtin_amdgcn_mfma_f32_16x16x32_bf16(bk[ni], aq[0][kk], s[ni][0], 0, 0, 0);
    }
    __builtin_amdgcn_s_setprio(0);
    if (maskB) {
#pragma unroll
      for (int ni = 0; ni < 8; ++ni)
#pragma unroll
        for (int r = 0; r < 4; ++r) {
          int kg = kb + ni * 16 + qg * 4 + r;
          if (kg > q0b + c) s[ni][1][r] = -1e30f;
        }
    }
    if (both && maskA) {
#pragma unroll
      for (int ni = 0; ni < 8; ++ni)
#pragma unroll
        for (int r = 0; r < 4; ++r) {
          int kg = kb + ni * 16 + qg * 4 + r;
          if (kg > q0a + c) s[ni][0][r] = -1e30f;
        }
    }
    softmaxRow(1, s);
    if (both) softmaxRow(0, s);
    // P -> per-wave LDS (full 128-wide, no reuse hazard)
    unsigned short* P = Pl[wave];
#pragma unroll
    for (int ni = 0; ni < 8; ++ni) {
      {
        bf16x4 pk;
#pragma unroll
        for (int r = 0; r < 4; ++r) pk[r] = (__bf16)s[ni][1][r];
        *(bf16x4*)&P[(16 + c) * 136 + ni * 16 + qg * 4] = pk;
      }
      if (both) {
        bf16x4 pk;
#pragma unroll
        for (int r = 0; r < 4; ++r) pk[r] = (__bf16)s[ni][0][r];
        *(bf16x4*)&P[c * 136 + ni * 16 + qg * 4] = pk;
      }
    }
    // PV
    __builtin_amdgcn_s_setprio(1);
#pragma unroll
    for (int ch = 0; ch < 2; ++ch)
#pragma unroll
      for (int kk = 0; kk < 2; ++kk) {
        bf16x8 bv[4];
#pragma unroll
        for (int nd = 0; nd < 4; ++nd) {
          int dd = nd * 16 + c;
          int f = ((dd >> 3) ^ dd) & 7;
          int crd = kk * 4 + qg;
          bv[nd] = *(const bf16x8*)&Vt[kbuf][ch][dd * 72 + ((crd ^ f) << 3)];
        }
        bf16x8 pa1 = *(const bf16x8*)&P[(16 + c) * 136 + ch * 64 + kk * 32 + qg * 8];
#pragma unroll
        for (int nd = 0; nd < 4; ++nd)
          aco[1][nd] = __builtin_amdgcn_mfma_f32_16x16x32_bf16(pa1, bv[nd], aco[1][nd], 0, 0, 0);
        if (both) {
          bf16x8 pa0 = *(const bf16x8*)&P[c * 136 + ch * 64 + kk * 32 + qg * 8];
#pragma unroll
          for (int nd = 0; nd < 4; ++nd)
            aco[0][nd] = __builtin_amdgcn_mfma_f32_16x16x32_bf16(pa0, bv[nd], aco[0][nd], 0, 0, 0);
        }
      }
    __builtin_amdgcn_s_setprio(0);
  };

  // prologue: tile 0
  stageK(0, 0);
  {
    u16x8 v0[2];
    loadV(0, v0);
    writeV(0, v0);
  }
  __syncthreads();
  int kbuf = 0;
  for (int t = 0; t < nit; ++t) {
    const int kb = t * 128;
    const bool hn = (t + 1 < nit);
    u16x8 vn[2];
    if (hn) { stageK(kb + 128, kbuf ^ 1); loadV(kb + 128, vn); }
    computeTile(kb, kbuf, t <= p, t == p, t == nit - 1);
    if (hn) writeV(kbuf ^ 1, vn);
    __syncthreads();
    kbuf ^= 1;
  }

  // epilogue: O /= l
  unsigned short* outp = ctx + (size_t)b * T_SZ * DMODEL + h * HD;
#pragma unroll
  for (int mi = 0; mi < 2; ++mi) {
    float linv = 1.f / lst[mi];
#pragma unroll
    for (int r = 0; r < 4; ++r) {
      float inv = __shfl(linv, qg * 20 + r, 64);
      int q = (mi ? q0b : q0a) + qg * 4 + r;
#pragma unroll
      for (int nd = 0; nd < 4; ++nd)
        outp[(size_t)q * DMODEL + nd * 16 + c] = f2bf(aco[mi][nd][r] * inv);
    }
  }
}

extern "C" void kernel_launch(void* const* d_in, const int* in_sizes, int n_in,
                              void* d_out, int out_size, void* d_ws, size_t ws_size,
                              hipStream_t stream) {
  const float* x = (const float*)d_in[0];
  const float* nw = (const float*)d_in[1];
  const float* qkv_w = (const float*)d_in[2];
  const float* out_w = (const float*)d_in[3];
  float* out = (float*)d_out;

  unsigned short* ws = (unsigned short*)d_ws;
  unsigned short* xn = ws;
  unsigned short* qkvw = xn + (size_t)MROWS * DMODEL;
  unsigned short* outw = qkvw + (size_t)3 * DMODEL * DMODEL;
  unsigned short* qkv = outw + (size_t)DMODEL * DMODEL;
  unsigned short* ctx = qkv + (size_t)MROWS * 3 * DMODEL;

  cvt_all<<<dim3(4096), dim3(256), 0, stream>>>(qkv_w, out_w, qkvw);
  rmsnorm_bf16<<<dim3(MROWS), dim3(256), 0, stream>>>(x, nw, xn);
  gemm_bt<0><<<dim3(768), dim3(256), 0, stream>>>(xn, qkvw, qkv, MROWS, 3 * DMODEL, DMODEL, 24);
  attn_causal<<<dim3(256), dim3(512), 0, stream>>>(qkv, ctx);
  gemm_bt<1><<<dim3(256), dim3(256), 0, stream>>>(ctx, outw, out, MROWS, DMODEL, DMODEL, 8);
}

// Round 6
// 122.626 us; speedup vs baseline: 1.1379x; 1.1379x over previous
//
#include <hip/hip_runtime.h>
#include <stdint.h>

#define B_SZ 2
#define T_SZ 2048
#define DMODEL 1024
#define HCNT 16
#define HD 64
#define MROWS (B_SZ * T_SZ)  // 4096

typedef __attribute__((ext_vector_type(8))) __bf16 bf16x8;
typedef __attribute__((ext_vector_type(4))) __bf16 bf16x4;
typedef __attribute__((ext_vector_type(4))) float f32x4;
typedef __attribute__((ext_vector_type(8))) unsigned short u16x8;

__device__ __forceinline__ unsigned short f2bf(float f) {
  union { float f; uint32_t u; } v; v.f = f;
  uint32_t u = v.u;
  u += 0x7fffu + ((u >> 16) & 1u);
  return (unsigned short)(u >> 16);
}

__device__ __forceinline__ float fexp2(float x) {
#if __has_builtin(__builtin_amdgcn_exp2f)
  return __builtin_amdgcn_exp2f(x);
#else
  return exp2f(x);
#endif
}

__device__ __forceinline__ void gld_lds16(const void* g, void* l) {
  __builtin_amdgcn_global_load_lds((__attribute__((address_space(1))) void*)(uintptr_t)g,
                                   (__attribute__((address_space(3))) void*)l, 16, 0, 0);
}

// ---------------- fp32 -> bf16 convert (both weight tensors, one launch) ----
__global__ __launch_bounds__(256)
void cvt_all(const float* __restrict__ qkv_w, const float* __restrict__ out_w,
             unsigned short* __restrict__ dst) {
  int i = blockIdx.x * 256 + threadIdx.x;
  const int n1 = 3 * DMODEL * DMODEL / 4;
  float4 v = (i < n1) ? ((const float4*)qkv_w)[i] : ((const float4*)out_w)[i - n1];
  ushort4 o;
  o.x = f2bf(v.x); o.y = f2bf(v.y); o.z = f2bf(v.z); o.w = f2bf(v.w);
  ((ushort4*)dst)[i] = o;
}

// ---------------- RMSNorm (fp32 in, bf16 out) ----------------
__global__ __launch_bounds__(256)
void rmsnorm_bf16(const float* __restrict__ x, const float* __restrict__ w,
                  unsigned short* __restrict__ xn) {
  const int row = blockIdx.x;
  const int t = threadIdx.x;
  float4 v = ((const float4*)(x + (size_t)row * DMODEL))[t];
  float ss = v.x * v.x + v.y * v.y + v.z * v.z + v.w * v.w;
#pragma unroll
  for (int o = 1; o < 64; o <<= 1) ss += __shfl_xor(ss, o, 64);
  __shared__ float red[4];
  if ((t & 63) == 0) red[t >> 6] = ss;
  __syncthreads();
  float tot = red[0] + red[1] + red[2] + red[3];
  float scale = rsqrtf(tot * (1.0f / (float)DMODEL) + 1e-6f);
  float4 wv = ((const float4*)w)[t];
  ushort4 o;
  o.x = f2bf(v.x * scale * wv.x);
  o.y = f2bf(v.y * scale * wv.y);
  o.z = f2bf(v.z * scale * wv.z);
  o.w = f2bf(v.w * scale * wv.w);
  ((ushort4*)(xn + (size_t)row * DMODEL))[t] = o;
}

// ---------------- bf16 NT GEMM: C[M][N] = A[M][K] * B[N][K]^T, BK=64 --------
// T2 XOR-swizzle: 128B row stride would put all 16 fragment rows on one bank.
// Source chunk pre-swizzled (chunk ^= row&7), LDS linear, read XORs the same.
__device__ __forceinline__ void stage128x64(const unsigned short* g, int ldg,
                                            unsigned short* lds, int tid) {
  const int wave = tid >> 6;
#pragma unroll
  for (int i = 0; i < 4; ++i) {
    int row = i * 32 + (tid >> 3);
    const unsigned short* gp = g + (size_t)row * ldg + (((tid & 7) ^ (row & 7)) << 3);
    gld_lds16(gp, lds + i * 2048 + wave * 512);
  }
}

template <int F32OUT>
__global__ __launch_bounds__(256, 2)
void gemm_bt(const unsigned short* __restrict__ A, const unsigned short* __restrict__ B,
             void* __restrict__ Cv, int M, int N, int K, int nbx) {
  __shared__ __align__(16) unsigned short As[2][128 * 64];
  __shared__ __align__(16) unsigned short Bs[2][128 * 64];
  const int t = threadIdx.x, wave = t >> 6, lane = t & 63;
  const int cpx = gridDim.x >> 3;
  const int swz = (blockIdx.x & 7) * cpx + (blockIdx.x >> 3);
  const int m0 = (swz / nbx) * 128, n0 = (swz % nbx) * 128;
  const int wr = wave >> 1, wc = wave & 1;
  const int c = lane & 15, qg = lane >> 4;
  f32x4 acc[4][4] = {};
  const int nk = K >> 6;
  stage128x64(A + (size_t)m0 * K, K, As[0], t);
  stage128x64(B + (size_t)n0 * K, K, Bs[0], t);
  __syncthreads();
  int buf = 0;
  for (int kt = 0; kt < nk; ++kt) {
    if (kt + 1 < nk) {
      stage128x64(A + (size_t)m0 * K + (kt + 1) * 64, K, As[buf ^ 1], t);
      stage128x64(B + (size_t)n0 * K + (kt + 1) * 64, K, Bs[buf ^ 1], t);
    }
#pragma unroll
    for (int kk = 0; kk < 2; ++kk) {
      bf16x8 af[4], bfr[4];
#pragma unroll
      for (int mi = 0; mi < 4; ++mi) {
        int row = wr * 64 + mi * 16 + c;
        af[mi] = *(const bf16x8*)&As[buf][row * 64 + (((kk * 4 + qg) ^ (row & 7)) << 3)];
      }
#pragma unroll
      for (int ni = 0; ni < 4; ++ni) {
        int row = wc * 64 + ni * 16 + c;
        bfr[ni] = *(const bf16x8*)&Bs[buf][row * 64 + (((kk * 4 + qg) ^ (row & 7)) << 3)];
      }
#pragma unroll
      for (int mi = 0; mi < 4; ++mi)
#pragma unroll
        for (int ni = 0; ni < 4; ++ni)
          acc[mi][ni] = __builtin_amdgcn_mfma_f32_16x16x32_bf16(af[mi], bfr[ni], acc[mi][ni], 0, 0, 0);
    }
    __syncthreads();
    buf ^= 1;
  }
  const int cr = qg * 4;
#pragma unroll
  for (int mi = 0; mi < 4; ++mi)
#pragma unroll
    for (int ni = 0; ni < 4; ++ni) {
      int row = m0 + wr * 64 + mi * 16 + cr;
      int col = n0 + wc * 64 + ni * 16 + c;
      if (F32OUT) {
        float* C = (float*)Cv;
#pragma unroll
        for (int r = 0; r < 4; ++r) C[(size_t)(row + r) * N + col] = acc[mi][ni][r];
      } else {
        unsigned short* C = (unsigned short*)Cv;
#pragma unroll
        for (int r = 0; r < 4; ++r) C[(size_t)(row + r) * N + col] = f2bf(acc[mi][ni][r]);
      }
    }
}

// ---------------- causal flash attention v5: fused q-tile pair ----------------
// 256 blocks (1/CU) x 512 threads (8 waves). Block (bh, p) owns q-tiles p and
// 15-p sharing ONE K/V stream (16-p k-tiles). Each wave: 16 rows of small tile
// (mi=0, active for t<=p) + 16 rows of big tile (mi=1, always). Total mi-units
// = 17 for every p -> perfectly uniform blocks, zero idle waves. One barrier
// per k-tile; K via global_load_lds (dbuf), V reg-staged (T14, dbuf).
__global__ __launch_bounds__(512, 2)
void attn_causal(const unsigned short* __restrict__ qkv, unsigned short* __restrict__ ctx) {
  __shared__ __align__(16) unsigned short Ks[2][128 * 64];     // 32 KB
  __shared__ __align__(16) unsigned short Vt[2][2][64 * 72];   // 36.9 KB
  __shared__ __align__(16) unsigned short Pl[8][32 * 136];     // 69.6 KB
  const int tid = threadIdx.x, wave = tid >> 6, lane = tid & 63;
  const int id = blockIdx.x;
  const int bh = (id & 7) | ((id >> 6) << 3);   // same bh -> same XCD
  const int p = (id >> 3) & 7;
  const int b = bh >> 4, h = bh & 15;
  const int q0a = p * 128 + wave * 16;          // mi=0 (small tile) rows
  const int q0b = (15 - p) * 128 + wave * 16;   // mi=1 (big tile) rows
  const int nit = 16 - p;
  const int c = lane & 15, qg = lane >> 4;
  const size_t base = (size_t)b * T_SZ * 3 * DMODEL;
  const int koffK = DMODEL + h * HD;
  const int koffV = 2 * DMODEL + h * HD;

  // Q fragments, pre-scaled by 0.125 * log2(e)
  const float QSC = 0.125f * 1.4426950408889634f;
  bf16x8 aq[2][2];
#pragma unroll
  for (int mi = 0; mi < 2; ++mi)
#pragma unroll
    for (int kk = 0; kk < 2; ++kk) {
      int q = (mi ? q0b : q0a) + c;
      bf16x8 f = *(const bf16x8*)(qkv + base + (size_t)q * 3 * DMODEL + h * HD + kk * 32 + qg * 8);
#pragma unroll
      for (int j = 0; j < 8; ++j) f[j] = (__bf16)((float)f[j] * QSC);
      aq[mi][kk] = f;
    }

  float mst[2] = {-3e38f, -3e38f}, lst[2] = {0.f, 0.f};
  f32x4 aco[2][4];
#pragma unroll
  for (int mi = 0; mi < 2; ++mi)
#pragma unroll
    for (int nd = 0; nd < 4; ++nd)
#pragma unroll
      for (int r = 0; r < 4; ++r) aco[mi][nd][r] = 0.f;

  auto stageK = [&](int kb, int bufi) {
#pragma unroll
    for (int i = 0; i < 2; ++i) {
      int row = i * 64 + (tid >> 3);
      gld_lds16(qkv + base + (size_t)(kb + row) * 3 * DMODEL + koffK + (((tid & 7) ^ (row & 7)) << 3),
                &Ks[bufi][i * 4096 + (wave << 9)]);
    }
  };
  auto loadV = [&](int kb, u16x8* v) {
#pragma unroll
    for (int i = 0; i < 2; ++i)
      v[i] = *(const u16x8*)(qkv + base + (size_t)(kb + i * 64 + (tid >> 3)) * 3 * DMODEL + koffV + (tid & 7) * 8);
  };
  auto writeV = [&](int bufi, const u16x8* v) {
#pragma unroll
    for (int i = 0; i < 2; ++i) {
      int kv = tid >> 3;              // k within chunk i (chunk = i*64)
#pragma unroll
      for (int j = 0; j < 8; ++j) {
        int dd = (tid & 7) * 8 + j;
        int f = (tid & 7) ^ j;        // ((dd>>3)^dd)&7
        Vt[bufi][i][dd * 72 + ((((kv >> 3) ^ f) << 3) | (kv & 7))] = v[i][j];
      }
    }
  };

  auto softmaxRow = [&](int mi, f32x4 s[8][2]) {
    float rm = -3e38f;
#pragma unroll
    for (int ni = 0; ni < 8; ++ni)
#pragma unroll
      for (int r = 0; r < 4; ++r) rm = fmaxf(rm, s[ni][mi][r]);
    rm = fmaxf(rm, __shfl_xor(rm, 16, 64));
    rm = fmaxf(rm, __shfl_xor(rm, 32, 64));
    float mo = mst[mi];
    float mn = mo;
    if (__any(rm > mo + 11.5f)) {
      mn = fmaxf(mo, rm);
      float corr = fexp2(mo - mn);
      lst[mi] *= corr;
      mst[mi] = mn;
#pragma unroll
      for (int r = 0; r < 4; ++r) {
        float cr = __shfl(corr, qg * 20 + r, 64);
#pragma unroll
        for (int nd = 0; nd < 4; ++nd) aco[mi][nd][r] *= cr;
      }
    }
    float rs = 0.f;
#pragma unroll
    for (int ni = 0; ni < 8; ++ni)
#pragma unroll
      for (int r = 0; r < 4; ++r) {
        float pv = fexp2(s[ni][mi][r] - mn);
        s[ni][mi][r] = pv;
        rs += pv;
      }
    rs += __shfl_xor(rs, 16, 64);
    rs += __shfl_xor(rs, 32, 64);
    lst[mi] += rs;
  };

  auto computeTile = [&](int kb, int kbuf, bool both, bool maskA, bool maskB) {
    f32x4 s[8][2] = {};
    __builtin_amdgcn_s_setprio(1);
#pragma unroll
    for (int kk = 0; kk < 2; ++kk) {
      bf16x8 bk[8];
#pragma unroll
      for (int ni = 0; ni < 8; ++ni) {
        int row = ni * 16 + c;
        int crd = kk * 4 + qg;
        bk[ni] = *(const bf16x8*)&Ks[kbuf][row * 64 + ((crd ^ (row & 7)) << 3)];
      }
#pragma unroll
      for (int ni = 0; ni < 8; ++ni)
        s[ni][1] = __builtin_amdgcn_mfma_f32_16x16x32_bf16(bk[ni], aq[1][kk], s[ni][1], 0, 0, 0);
      if (both)
#pragma unroll
        for (int ni = 0; ni < 8; ++ni)
          s[ni][0] = __builtin_amdgcn_mfma_f32_16x16x32_bf16(bk[ni], aq[0][kk], s[ni][0], 0, 0, 0);
    }
    __builtin_amdgcn_s_setprio(0);
    if (maskB) {
#pragma unroll
      for (int ni = 0; ni < 8; ++ni)
#pragma unroll
        for (int r = 0; r < 4; ++r) {
          int kg = kb + ni * 16 + qg * 4 + r;
          if (kg > q0b + c) s[ni][1][r] = -1e30f;
        }
    }
    if (both && maskA) {
#pragma unroll
      for (int ni = 0; ni < 8; ++ni)
#pragma unroll
        for (int r = 0; r < 4; ++r) {
          int kg = kb + ni * 16 + qg * 4 + r;
          if (kg > q0a + c) s[ni][0][r] = -1e30f;
        }
    }
    softmaxRow(1, s);
    if (both) softmaxRow(0, s);
    // P -> per-wave LDS (full 128-wide, no reuse hazard)
    unsigned short* P = Pl[wave];
#pragma unroll
    for (int ni = 0; ni < 8; ++ni) {
      {
        bf16x4 pk;
#pragma unroll
        for (int r = 0; r < 4; ++r) pk[r] = (__bf16)s[ni][1][r];
        *(bf16x4*)&P[(16 + c) * 136 + ni * 16 + qg * 4] = pk;
      }
      if (both) {
        bf16x4 pk;
#pragma unroll
        for (int r = 0; r < 4; ++r) pk[r] = (__bf16)s[ni][0][r];
        *(bf16x4*)&P[c * 136 + ni * 16 + qg * 4] = pk;
      }
    }
    // PV
    __builtin_amdgcn_s_setprio(1);
#pragma unroll
    for (int ch = 0; ch < 2; ++ch)
#pragma unroll
      for (int kk = 0; kk < 2; ++kk) {
        bf16x8 bv[4];
#pragma unroll
        for (int nd = 0; nd < 4; ++nd) {
          int dd = nd * 16 + c;
          int f = ((dd >> 3) ^ dd) & 7;
          int crd = kk * 4 + qg;
          bv[nd] = *(const bf16x8*)&Vt[kbuf][ch][dd * 72 + ((crd ^ f) << 3)];
        }
        bf16x8 pa1 = *(const bf16x8*)&P[(16 + c) * 136 + ch * 64 + kk * 32 + qg * 8];
#pragma unroll
        for (int nd = 0; nd < 4; ++nd)
          aco[1][nd] = __builtin_amdgcn_mfma_f32_16x16x32_bf16(pa1, bv[nd], aco[1][nd], 0, 0, 0);
        if (both) {
          bf16x8 pa0 = *(const bf16x8*)&P[c * 136 + ch * 64 + kk * 32 + qg * 8];
#pragma unroll
          for (int nd = 0; nd < 4; ++nd)
            aco[0][nd] = __builtin_amdgcn_mfma_f32_16x16x32_bf16(pa0, bv[nd], aco[0][nd], 0, 0, 0);
        }
      }
    __builtin_amdgcn_s_setprio(0);
  };

  // prologue: tile 0
  stageK(0, 0);
  {
    u16x8 v0[2];
    loadV(0, v0);
    writeV(0, v0);
  }
  __syncthreads();
  int kbuf = 0;
  for (int t = 0; t < nit; ++t) {
    const int kb = t * 128;
    const bool hn = (t + 1 < nit);
    u16x8 vn[2];
    if (hn) { stageK(kb + 128, kbuf ^ 1); loadV(kb + 128, vn); }
    computeTile(kb, kbuf, t <= p, t == p, t == nit - 1);
    if (hn) writeV(kbuf ^ 1, vn);
    __syncthreads();
    kbuf ^= 1;
  }

  // epilogue: O /= l
  unsigned short* outp = ctx + (size_t)b * T_SZ * DMODEL + h * HD;
#pragma unroll
  for (int mi = 0; mi < 2; ++mi) {
    float linv = 1.f / lst[mi];
#pragma unroll
    for (int r = 0; r < 4; ++r) {
      float inv = __shfl(linv, qg * 20 + r, 64);
      int q = (mi ? q0b : q0a) + qg * 4 + r;
#pragma unroll
      for (int nd = 0; nd < 4; ++nd)
        outp[(size_t)q * DMODEL + nd * 16 + c] = f2bf(aco[mi][nd][r] * inv);
    }
  }
}

extern "C" void kernel_launch(void* const* d_in, const int* in_sizes, int n_in,
                              void* d_out, int out_size, void* d_ws, size_t ws_size,
                              hipStream_t stream) {
  const float* x = (const float*)d_in[0];
  const float* nw = (const float*)d_in[1];
  const float* qkv_w = (const float*)d_in[2];
  const float* out_w = (const float*)d_in[3];
  float* out = (float*)d_out;

  unsigned short* ws = (unsigned short*)d_ws;
  unsigned short* xn = ws;
  unsigned short* qkvw = xn + (size_t)MROWS * DMODEL;
  unsigned short* outw = qkvw + (size_t)3 * DMODEL * DMODEL;
  unsigned short* qkv = outw + (size_t)DMODEL * DMODEL;
  unsigned short* ctx = qkv + (size_t)MROWS * 3 * DMODEL;

  cvt_all<<<dim3(4096), dim3(256), 0, stream>>>(qkv_w, out_w, qkvw);
  rmsnorm_bf16<<<dim3(MROWS), dim3(256), 0, stream>>>(x, nw, xn);
  gemm_bt<0><<<dim3(768), dim3(256), 0, stream>>>(xn, qkvw, qkv, MROWS, 3 * DMODEL, DMODEL, 24);
  attn_causal<<<dim3(256), dim3(512), 0, stream>>>(qkv, ctx);
  gemm_bt<1><<<dim3(256), dim3(256), 0, stream>>>(ctx, outw, out, MROWS, DMODEL, DMODEL, 8);
}